// Round 9
// baseline (592.261 us; speedup 1.0000x reference)
//
#include <hip/hip_runtime.h>

#define T_OBS 512
#define RSTRH 296          // halves per batch-row (148 dw; quad-stride 37 == 5 mod 8 -> spread)
#define PSTR  28           // s_pr row stride (dwords, 24 used)
#define L2E   1.44269504089f

typedef float    f32x4 __attribute__((ext_vector_type(4)));
typedef _Float16 f16x8 __attribute__((ext_vector_type(8)));

#define MF(A,B,C) __builtin_amdgcn_mfma_f32_16x16x32_f16(A,B,C,0,0,0)

__device__ __forceinline__ unsigned f2h(float f){
    union { _Float16 h; unsigned short u; } v; v.h=(_Float16)f; return (unsigned)v.u;
}

// prescaled gates: i,f,o carry -log2e; g carries +2*log2e.
// single-rcp gates: R = rcp(ui*uf*ug*uo); recover all four via products. 5 exp2 + 2 rcp.
__device__ __forceinline__ float act1(const f32x4 a, float& c){
    const float Ei=__builtin_amdgcn_exp2f(a[0]), Ef=__builtin_amdgcn_exp2f(a[1]);
    const float Eg=__builtin_amdgcn_exp2f(a[2]), Eo=__builtin_amdgcn_exp2f(a[3]);
    const float ui=1.f+Ei, uf=1.f+Ef, ug=1.f+Eg, uo=1.f+Eo;
    const float P=ui*uf, Q=ug*uo;
    const float R=__builtin_amdgcn_rcpf(P*Q);
    const float aP=R*Q, aQ=R*P;
    const float ig=aP*uf, fg=aP*ui;
    const float og=aQ*ug;
    const float gg=fmaf(aQ*uo,-2.f,1.f);
    c = fg*c + ig*gg;
    const float Ec=__builtin_amdgcn_exp2f(2.f*L2E*c);
    return og*fmaf(__builtin_amdgcn_rcpf(1.f+Ec),-2.f,1.f);
}

// sigma layout: stored position p holds unit 8*(p>>3) + 4*(p&1) + ((p&7)>>1)
__device__ __forceinline__ int u_of_pos(const int p){
    return 8*(p>>3) + 4*(p&1) + ((p&7)>>1);
}

// packed progress counter: low16 = L0 wave-tick completions, high16 = L1.
__device__ __forceinline__ void spin_ge(volatile unsigned* pc, unsigned t0, unsigned t1){
    unsigned v = *pc;
    while (((v & 0xffffu) < t0) || ((v >> 16) < t1)) {
        __builtin_amdgcn_s_sleep(1);
        v = *pc;
    }
    asm volatile("" ::: "memory");
}

// h regions: 3 parities x 96 halves per batch-row: region r at 96r; h0 pos 0..47, h1 pos 48..95.
__global__ __launch_bounds__(768, 1) void lstm2_v9(
    const float* __restrict__ x,
    const float* __restrict__ Wih0, const float* __restrict__ Whh0,
    const float* __restrict__ bih0, const float* __restrict__ bhh0,
    const float* __restrict__ Wih1, const float* __restrict__ Whh1,
    const float* __restrict__ bih1, const float* __restrict__ bhh1,
    const float* __restrict__ Wlin, const float* __restrict__ blin,
    const int* __restrict__ fut,
    float* __restrict__ out)
{
    __shared__ __attribute__((aligned(16))) _Float16 s_h[16 * RSTRH];
    __shared__ __attribute__((aligned(16))) float s_pr[3][16 * PSTR];
    __shared__ unsigned s_cnt;
    unsigned* const s32 = (unsigned*)s_h;
    volatile unsigned* const pcv = (volatile unsigned*)&s_cnt;

    const int tid  = threadIdx.x;
    const int wave = tid >> 6, lane = tid & 63;
    const int q    = lane & 15, rg = lane >> 4;
    const bool isL1 = (wave >= 6);
    const int  w    = isL1 ? wave - 6 : wave;

    for (int i = tid; i < 16 * RSTRH; i += 768) s_h[i] = (_Float16)0.f;
    if (tid == 0) s_cnt = 0u;

    const float sgl = ((q & 3) == 2) ? 2.f * L2E : -L2E;

    // ---- A fragments (2 tiles/wave), prescaled, fp16 hi/lo, sigma-permuted k-cols ----
    f16x8 ah[2][3], al[2][3];
    #pragma unroll
    for (int i = 0; i < 2; ++i) {
        const int t  = 2 * w + i;
        const int rp = 16 * t + q;
        const int r0 = (rp & 3) * 48 + (rp >> 2);
        #pragma unroll
        for (int s = 0; s < 3; ++s)
            #pragma unroll
            for (int j = 0; j < 8; ++j) {
                const int p = 32 * s + 8 * rg + j;
                float v = 0.f;
                if (isL1) v = ((p < 48) ? Wih1[r0 * 48 + u_of_pos(p)]
                                        : Whh1[r0 * 48 + u_of_pos(p - 48)]) * sgl;
                else if (p < 48) v = Whh0[r0 * 48 + u_of_pos(p)] * sgl;
                const _Float16 hi = (_Float16)v;
                ah[i][s][j] = hi;
                al[i][s][j] = (_Float16)(v - (float)hi);
            }
    }

    const float sg4[4] = { -L2E, -L2E, 2.f * L2E, -L2E };
    f32x4 bvt[2], wi0v[2];
    float wlq[2];
    #pragma unroll
    for (int i = 0; i < 2; ++i) {
        const int u = 8 * w + 4 * i + rg;
        wlq[i] = Wlin[u];
        #pragma unroll
        for (int g = 0; g < 4; ++g) {
            bvt[i][g]  = (isL1 ? (bih1[g*48+u] + bhh1[g*48+u])
                               : (bih0[g*48+u] + bhh0[g*48+u])) * sg4[g];
            wi0v[i][g] = Wih0[g * 48 + u] * sg4[g];
        }
    }

    const int ko0 = 8 * rg, ko1 = 32 + 8 * rg, ko2 = 64 + 8 * rg;  // branch-free
    const int F    = fut[0];
    const int TT   = T_OBS + F;
    const int bb0  = blockIdx.x * 16;
    const float bl = blin[0];
    const int xrow = (bb0 + q) * T_OBS;
    const int nbh  = q * RSTRH;
    const int hw0  = nbh + 8 * w + 2 * rg;          // + 96*region (+48 for L1)
    const int prw  = q * PSTR + 4 * w + rg;

    float cc0 = 0.f, cc1 = 0.f;

    __syncthreads();   // init visible; the ONLY barrier in the kernel

    // ---- tick 0 (peeled): L0 writes h0(0) into region 0; both groups count ----
    if (!isL1) {
        const float x0 = x[xrow];
        const f32x4 a0 = bvt[0] + wi0v[0] * x0;
        const f32x4 a1 = bvt[1] + wi0v[1] * x0;
        const unsigned h0p = f2h(act1(a0, cc0));
        const unsigned h1p = f2h(act1(a1, cc1));
        s32[hw0 >> 1] = h0p | (h1p << 16);
        asm volatile("s_waitcnt lgkmcnt(0)" ::: "memory");
        if (lane == 0) atomicAdd(&s_cnt, 1u);
    } else {
        if (lane == 0) atomicAdd(&s_cnt, 1u << 16);
    }
    float xcur = isL1 ? 0.f : x[xrow + 1];

    // steady tick: L0 computes step TAU_, L1 computes step TAU_-1.
    // WR_ = write region (TAU_%3), RR_ = read region ((TAU_-1)%3), GB_ = gather parity ((TAU_-2)%3).
#define STEADY(TAU_, WR_, RR_, GB_) do {                                         \
    const unsigned t0_ = 6u * (unsigned)(TAU_);                                  \
    if (!isL1) {                                                                 \
        spin_ge(pcv, t0_, t0_ - 6u);                                             \
        const float xnxt = x[xrow + (((TAU_) + 1 < T_OBS) ? (TAU_) + 1 : T_OBS - 1)]; \
        const f16x8 B0 = *(const f16x8*)(s_h + nbh + 96*(RR_) + ko0);            \
        const f16x8 B1 = *(const f16x8*)(s_h + nbh + 96*(RR_) + ko1);            \
        f32x4 g0 = MF(ah[0][0], B0, bvt[0]);                                     \
        g0 = MF(al[0][0], B0, g0);                                               \
        g0 = MF(ah[0][1], B1, g0);                                               \
        g0 = MF(al[0][1], B1, g0);                                               \
        f32x4 g1 = MF(ah[1][0], B0, bvt[1]);                                     \
        g1 = MF(al[1][0], B0, g1);                                               \
        g1 = MF(ah[1][1], B1, g1);                                               \
        g1 = MF(al[1][1], B1, g1);                                               \
        if ((TAU_) >= 3 && w < 4) {        /* deferred out step TAU_-3 */        \
            const int nn = 4 * w + rg;                                           \
            const float* pr = &s_pr[GB_][nn * PSTR];                             \
            float gv = pr[q] + ((q < 8) ? pr[16 + q] : 0.f);                     \
            gv += __shfl_xor(gv, 1); gv += __shfl_xor(gv, 2);                    \
            gv += __shfl_xor(gv, 4); gv += __shfl_xor(gv, 8);                    \
            if (q == 0) out[(bb0 + nn) * TT + ((TAU_) - 3)] = gv + bl;           \
        }                                                                        \
        g0 += wi0v[0] * xcur;                                                    \
        g1 += wi0v[1] * xcur;                                                    \
        const unsigned h0p = f2h(act1(g0, cc0));                                 \
        const unsigned h1p = f2h(act1(g1, cc1));                                 \
        s32[(hw0 + 96*(WR_)) >> 1] = h0p | (h1p << 16);                          \
        asm volatile("s_waitcnt lgkmcnt(0)" ::: "memory");                       \
        if (lane == 0) atomicAdd(&s_cnt, 1u);                                    \
        xcur = xnxt;                                                             \
    } else {                                                                     \
        spin_ge(pcv, t0_, t0_);                                                  \
        const f16x8 B0 = *(const f16x8*)(s_h + nbh + 96*(RR_) + ko0);            \
        const f16x8 B1 = *(const f16x8*)(s_h + nbh + 96*(RR_) + ko1);            \
        const f16x8 B2 = *(const f16x8*)(s_h + nbh + 96*(RR_) + ko2);            \
        f32x4 g0 = MF(ah[0][0], B0, bvt[0]);                                     \
        g0 = MF(al[0][0], B0, g0);                                               \
        g0 = MF(ah[0][1], B1, g0);                                               \
        g0 = MF(al[0][1], B1, g0);                                               \
        g0 = MF(ah[0][2], B2, g0);                                               \
        g0 = MF(al[0][2], B2, g0);                                               \
        f32x4 g1 = MF(ah[1][0], B0, bvt[1]);                                     \
        g1 = MF(al[1][0], B0, g1);                                               \
        g1 = MF(ah[1][1], B1, g1);                                               \
        g1 = MF(al[1][1], B1, g1);                                               \
        g1 = MF(ah[1][2], B2, g1);                                               \
        g1 = MF(al[1][2], B2, g1);                                               \
        const float h0f = act1(g0, cc0);                                         \
        const float h1f = act1(g1, cc1);                                         \
        s32[(hw0 + 96*(WR_) + 48) >> 1] = f2h(h0f) | (f2h(h1f) << 16);           \
        s_pr[WR_][prw] = fmaf(h1f, wlq[1], h0f * wlq[0]);                        \
        asm volatile("s_waitcnt lgkmcnt(0)" ::: "memory");                       \
        if (lane == 0) atomicAdd(&s_cnt, 1u << 16);                              \
    }                                                                            \
} while (0)

    // ---- steady loop: tau = 1..511, 3x unrolled with compile-time region parity ----
    for (int tau = 1; tau + 2 <= T_OBS - 1; tau += 3) {
        STEADY(tau,     1, 0, 2);   // tau % 3 == 1
        STEADY(tau + 1, 2, 1, 0);
        STEADY(tau + 2, 0, 2, 1);
    }
    STEADY(T_OBS - 1, 1, 0, 2);     // tau = 511 (511 % 3 == 1)

    // ---- AR loop: tau = 512..TT; runtime region parity; one-way same-tick handoff ----
    int wr = 2, rr = 1;             // 512%3, 511%3
    for (int tau = T_OBS; tau <= TT; ++tau) {
        const unsigned t0_ = 6u * (unsigned)tau;
        if (isL1) {
            spin_ge(pcv, t0_, t0_);
            const f16x8 B0 = *(const f16x8*)(s_h + nbh + 96*rr + ko0);
            const f16x8 B1 = *(const f16x8*)(s_h + nbh + 96*rr + ko1);
            const f16x8 B2 = *(const f16x8*)(s_h + nbh + 96*rr + ko2);
            f32x4 g0 = MF(ah[0][0], B0, bvt[0]);
            g0 = MF(al[0][0], B0, g0);
            g0 = MF(ah[0][1], B1, g0);
            g0 = MF(al[0][1], B1, g0);
            g0 = MF(ah[0][2], B2, g0);
            g0 = MF(al[0][2], B2, g0);
            f32x4 g1 = MF(ah[1][0], B0, bvt[1]);
            g1 = MF(al[1][0], B0, g1);
            g1 = MF(ah[1][1], B1, g1);
            g1 = MF(al[1][1], B1, g1);
            g1 = MF(ah[1][2], B2, g1);
            g1 = MF(al[1][2], B2, g1);
            const float h0f = act1(g0, cc0);
            const float h1f = act1(g1, cc1);
            s32[(hw0 + 96*wr + 48) >> 1] = f2h(h0f) | (f2h(h1f) << 16);
            s_pr[wr][prw] = fmaf(h1f, wlq[1], h0f * wlq[0]);
            asm volatile("s_waitcnt lgkmcnt(0)" ::: "memory");
            if (lane == 0) atomicAdd(&s_cnt, 1u << 16);
        } else {
            spin_ge(pcv, t0_, t0_ - 6u);
            const f16x8 B0 = *(const f16x8*)(s_h + nbh + 96*rr + ko0);
            const f16x8 B1 = *(const f16x8*)(s_h + nbh + 96*rr + ko1);
            f32x4 g0 = MF(ah[0][0], B0, bvt[0]);
            g0 = MF(al[0][0], B0, g0);
            g0 = MF(ah[0][1], B1, g0);
            g0 = MF(al[0][1], B1, g0);
            f32x4 g1 = MF(ah[1][0], B0, bvt[1]);
            g1 = MF(al[1][0], B0, g1);
            g1 = MF(ah[1][1], B1, g1);
            g1 = MF(al[1][1], B1, g1);
            if ((tau == T_OBS || tau == T_OBS + 1) && w < 4) {   // deferred 509, 510
                const int gb = (tau - 2) % 3;
                const int nn = 4 * w + rg;
                const float* pr = &s_pr[gb][nn * PSTR];
                float gv = pr[q] + ((q < 8) ? pr[16 + q] : 0.f);
                gv += __shfl_xor(gv, 1); gv += __shfl_xor(gv, 2);
                gv += __shfl_xor(gv, 4); gv += __shfl_xor(gv, 8);
                if (q == 0) out[(bb0 + nn) * TT + (tau - 3)] = gv + bl;
            }
            spin_ge(pcv, t0_, t0_ + 6u);          // wait L1 tick tau -> s_pr[wr] ready
            const float* pr = &s_pr[wr][q * PSTR];
            const f32x4 sv = *(const f32x4*)(pr)      + *(const f32x4*)(pr + 4)
                           + *(const f32x4*)(pr + 8)  + *(const f32x4*)(pr + 12)
                           + *(const f32x4*)(pr + 16) + *(const f32x4*)(pr + 20);
            const float o = sv[0] + sv[1] + sv[2] + sv[3] + bl;
            if (tid < 16) out[(bb0 + q) * TT + (tau - 1)] = o;
            if (tau < TT) {
                g0 += wi0v[0] * o;
                g1 += wi0v[1] * o;
                const unsigned h0p = f2h(act1(g0, cc0));
                const unsigned h1p = f2h(act1(g1, cc1));
                s32[(hw0 + 96*wr) >> 1] = h0p | (h1p << 16);
            }
            asm volatile("s_waitcnt lgkmcnt(0)" ::: "memory");
            if (lane == 0) atomicAdd(&s_cnt, 1u);
        }
        wr = (wr == 2) ? 0 : wr + 1;
        rr = (rr == 2) ? 0 : rr + 1;
    }
}

extern "C" void kernel_launch(void* const* d_in, const int* in_sizes, int n_in,
                              void* d_out, int out_size, void* d_ws, size_t ws_size,
                              hipStream_t stream) {
    const float* x    = (const float*)d_in[0];
    const float* Wih0 = (const float*)d_in[1];
    const float* Whh0 = (const float*)d_in[2];
    const float* bih0 = (const float*)d_in[3];
    const float* bhh0 = (const float*)d_in[4];
    const float* Wih1 = (const float*)d_in[5];
    const float* Whh1 = (const float*)d_in[6];
    const float* bih1 = (const float*)d_in[7];
    const float* bhh1 = (const float*)d_in[8];
    const float* Wlin = (const float*)d_in[9];
    const float* blin = (const float*)d_in[10];
    const int*   fut  = (const int*)d_in[11];
    float* out = (float*)d_out;

    const int B    = in_sizes[0] / T_OBS;   // 4096
    const int grid = B / 16;                // 256 blocks -> 1 per CU, 12 waves = 3/SIMD
    lstm2_v9<<<grid, 768, 0, stream>>>(
        x, Wih0, Whh0, bih0, bhh0, Wih1, Whh1, bih1, bhh1, Wlin, blin, fut, out);
}

// Round 11
// 511.362 us; speedup vs baseline: 1.1582x; 1.1582x over previous
//
#include <hip/hip_runtime.h>

#define T_OBS 512
#define RSTRH 264          // halves per batch-row (132 dw)
#define PSTR  28           // s_pr row stride (dwords)
#define L2E   1.44269504089f

typedef float    f32x4 __attribute__((ext_vector_type(4)));
typedef _Float16 f16x8 __attribute__((ext_vector_type(8)));

#define MF(A,B,C) __builtin_amdgcn_mfma_f32_16x16x32_f16(A,B,C,0,0,0)

__device__ __forceinline__ unsigned f2h(float f){
    union { _Float16 h; unsigned short u; } v; v.h=(_Float16)f; return (unsigned)v.u;
}

// barrier that waits ONLY on LDS (lgkmcnt) -- leaves out-stores / x-loads in flight.
// __syncthreads() would drain vmcnt(0), serializing global store retirement into every tick.
__device__ __forceinline__ void bar_lds(){
    asm volatile("s_waitcnt lgkmcnt(0)" ::: "memory");
    __builtin_amdgcn_sched_barrier(0);
    __builtin_amdgcn_s_barrier();
    __builtin_amdgcn_sched_barrier(0);
}

// prescaled gates: i,f,o carry -log2e; g carries +2*log2e.
// single-rcp gates: R = rcp(ui*uf*ug*uo); recover all four via products. 5 exp2 + 2 rcp.
__device__ __forceinline__ float act1(const f32x4 a, float& c){
    const float Ei=__builtin_amdgcn_exp2f(a[0]), Ef=__builtin_amdgcn_exp2f(a[1]);
    const float Eg=__builtin_amdgcn_exp2f(a[2]), Eo=__builtin_amdgcn_exp2f(a[3]);
    const float ui=1.f+Ei, uf=1.f+Ef, ug=1.f+Eg, uo=1.f+Eo;
    const float P=ui*uf, Q=ug*uo;
    const float R=__builtin_amdgcn_rcpf(P*Q);
    const float aP=R*Q, aQ=R*P;                 // 1/(ui*uf), 1/(ug*uo)
    const float ig=aP*uf, fg=aP*ui;             // sigmoids
    const float og=aQ*ug;
    const float gg=fmaf(aQ*uo,-2.f,1.f);        // tanh(g)
    c = fg*c + ig*gg;
    const float Ec=__builtin_amdgcn_exp2f(2.f*L2E*c);
    return og*fmaf(__builtin_amdgcn_rcpf(1.f+Ec),-2.f,1.f);
}

// sigma store layout: stored position p holds unit 8*(p>>3) + 4*(p&1) + ((p&7)>>1)
// (so lane (q,rg) of wave w writes its two units at adjacent halves 8w+2rg+{0,1})
__device__ __forceinline__ int u_of_pos(const int p){
    return 8*(p>>3) + 4*(p&1) + ((p&7)>>1);
}

// LDS per batch-row q (halves, stride RSTRH):
//   [0,48) h0 par0 | [48,64) pad0 | [64,112) h0 par1 | [112,128) pad0
//   [128,176) h1 par0 | [176,192) pad | [192,240) h1 par1 | [240,264) pad
__global__ __launch_bounds__(768, 1) void lstm2_v10(
    const float* __restrict__ x,
    const float* __restrict__ Wih0, const float* __restrict__ Whh0,
    const float* __restrict__ bih0, const float* __restrict__ bhh0,
    const float* __restrict__ Wih1, const float* __restrict__ Whh1,
    const float* __restrict__ bih1, const float* __restrict__ bhh1,
    const float* __restrict__ Wlin, const float* __restrict__ blin,
    const int* __restrict__ fut,
    float* __restrict__ out)
{
    __shared__ __attribute__((aligned(16))) _Float16 s_h[16 * RSTRH];
    __shared__ __attribute__((aligned(16))) float s_pr[2][16 * PSTR];
    unsigned* const s32 = (unsigned*)s_h;

    const int tid  = threadIdx.x;
    const int wave = tid >> 6, lane = tid & 63;
    const int q    = lane & 15, rg = lane >> 4;
    const bool isL1 = (wave >= 6);          // waves 0-5: layer 0; 6-11: layer 1
    const int  w    = isL1 ? wave - 6 : wave;

    for (int i = tid; i < 16 * RSTRH; i += 768) s_h[i] = (_Float16)0.f;

    // gate of this lane's A-rows: rp = 16t+q -> gate = q&3 (uniform per lane)
    const float sgl = ((q & 3) == 2) ? 2.f * L2E : -L2E;

    // ---- A fragments (2 tiles/wave), prescaled, fp16 hi/lo, sigma-permuted k-cols ----
    f16x8 ah[2][3], al[2][3];
    #pragma unroll
    for (int i = 0; i < 2; ++i) {
        const int t  = 2 * w + i;
        const int rp = 16 * t + q;
        const int r0 = (rp & 3) * 48 + (rp >> 2);
        #pragma unroll
        for (int s = 0; s < 3; ++s)
            #pragma unroll
            for (int j = 0; j < 8; ++j) {
                const int p = 32 * s + 8 * rg + j;
                float v = 0.f;
                if (isL1) v = ((p < 48) ? Wih1[r0 * 48 + u_of_pos(p)]
                                        : Whh1[r0 * 48 + u_of_pos(p - 48)]) * sgl;
                else if (p < 48) v = Whh0[r0 * 48 + u_of_pos(p)] * sgl;
                const _Float16 hi = (_Float16)v;
                ah[i][s][j] = hi;
                al[i][s][j] = (_Float16)(v - (float)hi);
            }
    }

    const float sg4[4] = { -L2E, -L2E, 2.f * L2E, -L2E };   // (i,f,g,o)
    f32x4 bvt[2], wi0v[2];
    float wlq[2];
    #pragma unroll
    for (int i = 0; i < 2; ++i) {
        const int u = 8 * w + 4 * i + rg;      // unit of this lane's act quad i
        wlq[i] = Wlin[u];
        #pragma unroll
        for (int g = 0; g < 4; ++g) {
            bvt[i][g]  = (isL1 ? (bih1[g*48+u] + bhh1[g*48+u])
                               : (bih0[g*48+u] + bhh0[g*48+u])) * sg4[g];
            wi0v[i][g] = Wih0[g * 48 + u] * sg4[g];
        }
    }

    // B-frag k-offsets (pre-parity): chunks never straddle the 48 boundary
    int koff[3];
    #pragma unroll
    for (int s = 0; s < 3; ++s) {
        const int p0 = 32 * s + 8 * rg;
        koff[s] = p0 + ((p0 >= 48) ? 80 : 0);   // h1 region sits +128 at p=48
    }

    const int F    = fut[0];
    const int TT   = T_OBS + F;
    const int bb0  = blockIdx.x * 16;
    const float bl = blin[0];
    const int xrow = (bb0 + q) * T_OBS;
    const int nbh  = q * RSTRH;
    const int hwp  = nbh + (isL1 ? 128 : 0) + 8 * w + 2 * rg;  // + CB at use (even)
    const int prw  = q * PSTR + 4 * w + rg;

    float cc0 = 0.f, cc1 = 0.f;
    const f32x4 z4 = { 0.f, 0.f, 0.f, 0.f };

    __syncthreads();

    // ---- tick 0 (peeled): h0(0) = act(bias + wi0*x0), h0(-1)=0 ----
    if (!isL1) {
        const float x0 = x[xrow];
        const f32x4 a0 = bvt[0] + wi0v[0] * x0;
        const f32x4 a1 = bvt[1] + wi0v[1] * x0;
        const unsigned h0 = f2h(act1(a0, cc0));
        const unsigned h1 = f2h(act1(a1, cc1));
        s32[hwp >> 1] = h0 | (h1 << 16);        // h0 par0 (CB=0)
    }
    bar_lds();
    float xcur = isL1 ? 0.f : x[xrow + 1];

    // steady tick: L0 computes step TAU_, L1 computes step TAU_-1; one barrier.
#define STEADY(TAU_, CB_, PB_) do {                                              \
    if (!isL1) {                                                                 \
        const float xnxt = x[xrow + (((TAU_) + 1 < T_OBS) ? (TAU_) + 1 : T_OBS - 1)]; \
        if ((TAU_) >= 2 && wave == 0) {        /* lane-parallel head gather */   \
            const int nn = lane >> 2, j0 = lane & 3;                             \
            const float* pr = &s_pr[((TAU_) - 1) & 1][nn * PSTR];                \
            float sg = pr[j0] + pr[j0+4] + pr[j0+8] + pr[j0+12]                  \
                     + pr[j0+16] + pr[j0+20];                                    \
            sg += __shfl_xor(sg, 1); sg += __shfl_xor(sg, 2);                    \
            if (j0 == 0) out[(bb0 + nn) * TT + ((TAU_) - 2)] = sg + bl;          \
        }                                                                        \
        const f16x8 B0 = *(const f16x8*)(s_h + nbh + (PB_) + koff[0]);           \
        const f16x8 B1 = *(const f16x8*)(s_h + nbh + (PB_) + koff[1]);           \
        f32x4 Aq[2], Bq[2];                                                      \
        _Pragma("unroll")                                                        \
        for (int i = 0; i < 2; ++i) {                                            \
            Aq[i] = MF(ah[i][0], B0, bvt[i]);                                    \
            Aq[i] = MF(al[i][0], B0, Aq[i]);                                     \
            Bq[i] = MF(ah[i][1], B1, z4);                                        \
            Bq[i] = MF(al[i][1], B1, Bq[i]);                                     \
        }                                                                        \
        const f32x4 a0 = Aq[0] + Bq[0] + wi0v[0] * xcur;                         \
        const f32x4 a1 = Aq[1] + Bq[1] + wi0v[1] * xcur;                         \
        const unsigned h0 = f2h(act1(a0, cc0));                                  \
        const unsigned h1 = f2h(act1(a1, cc1));                                  \
        s32[(hwp + (CB_)) >> 1] = h0 | (h1 << 16);                               \
        xcur = xnxt;                                                             \
    } else {                                                                     \
        const f16x8 B0 = *(const f16x8*)(s_h + nbh + (PB_) + koff[0]);           \
        const f16x8 B1 = *(const f16x8*)(s_h + nbh + (PB_) + koff[1]);           \
        const f16x8 B2 = *(const f16x8*)(s_h + nbh + (PB_) + koff[2]);           \
        f32x4 Aq[2], Bq[2];                                                      \
        _Pragma("unroll")                                                        \
        for (int i = 0; i < 2; ++i) {                                            \
            Aq[i] = MF(ah[i][0], B0, bvt[i]);                                    \
            Aq[i] = MF(al[i][0], B0, Aq[i]);                                     \
            Aq[i] = MF(ah[i][1], B1, Aq[i]);                                     \
            Bq[i] = MF(al[i][1], B1, z4);                                        \
            Bq[i] = MF(ah[i][2], B2, Bq[i]);                                     \
            Bq[i] = MF(al[i][2], B2, Bq[i]);                                     \
        }                                                                        \
        const f32x4 a0 = Aq[0] + Bq[0];                                          \
        const f32x4 a1 = Aq[1] + Bq[1];                                          \
        const float h0 = act1(a0, cc0);                                          \
        const float h1 = act1(a1, cc1);                                          \
        s32[(hwp + (CB_)) >> 1] = f2h(h0) | (f2h(h1) << 16);                     \
        s_pr[(TAU_) & 1][prw] = fmaf(h1, wlq[1], h0 * wlq[0]);                   \
    }                                                                            \
    bar_lds();                                                                   \
} while (0)

    // ---- steady loop: tau = 1..511, 2x unrolled with compile-time parity ----
    for (int tau = 1; tau < T_OBS - 1; tau += 2) {
        STEADY(tau,     64, 0);    // tau odd
        STEADY(tau + 1,  0, 64);   // tau+1 even
    }
    STEADY(T_OBS - 1, 64, 0);      // tau = 511

    // bridge: out(510) from s_pr parity 1 (written at tau=511)
    if (tid < 16) {
        const float* pr = &s_pr[1][tid * PSTR];
        const f32x4 sv = *(const f32x4*)(pr)      + *(const f32x4*)(pr + 4)
                       + *(const f32x4*)(pr + 8)  + *(const f32x4*)(pr + 12)
                       + *(const f32x4*)(pr + 16) + *(const f32x4*)(pr + 20);
        out[(bb0 + tid) * TT + (T_OBS - 2)] = sv[0] + sv[1] + sv[2] + sv[3] + bl;
    }

    // ---- AR loop: tau = 512..TT; o(tau-1) resolved mid-tick ----
    for (int tau = T_OBS; tau <= TT; ++tau) {
        const int cb = (tau & 1) * 64;
        const int pb = cb ^ 64;

        f32x4 Aq[2], Bq[2];
        if (isL1) {
            const f16x8 B0 = *(const f16x8*)(s_h + nbh + pb + koff[0]);
            const f16x8 B1 = *(const f16x8*)(s_h + nbh + pb + koff[1]);
            const f16x8 B2 = *(const f16x8*)(s_h + nbh + pb + koff[2]);
            #pragma unroll
            for (int i = 0; i < 2; ++i) {
                Aq[i] = MF(ah[i][0], B0, bvt[i]);
                Aq[i] = MF(al[i][0], B0, Aq[i]);
                Aq[i] = MF(ah[i][1], B1, Aq[i]);
                Bq[i] = MF(al[i][1], B1, z4);
                Bq[i] = MF(ah[i][2], B2, Bq[i]);
                Bq[i] = MF(al[i][2], B2, Bq[i]);
            }
            const f32x4 a0 = Aq[0] + Bq[0];
            const f32x4 a1 = Aq[1] + Bq[1];
            const float h0 = act1(a0, cc0);
            const float h1 = act1(a1, cc1);
            s32[(hwp + cb) >> 1] = f2h(h0) | (f2h(h1) << 16);
            s_pr[tau & 1][prw] = fmaf(h1, wlq[1], h0 * wlq[0]);
        } else {
            const f16x8 B0 = *(const f16x8*)(s_h + nbh + pb + koff[0]);
            const f16x8 B1 = *(const f16x8*)(s_h + nbh + pb + koff[1]);
            #pragma unroll
            for (int i = 0; i < 2; ++i) {
                Aq[i] = MF(ah[i][0], B0, bvt[i]);
                Aq[i] = MF(al[i][0], B0, Aq[i]);
                Bq[i] = MF(ah[i][1], B1, z4);
                Bq[i] = MF(al[i][1], B1, Bq[i]);
            }
        }
        bar_lds();   // mid: s_pr (h1(tau-1) partials) ready

        if (!isL1) {
            const float* pr = &s_pr[tau & 1][q * PSTR];
            const f32x4 sv = *(const f32x4*)(pr)      + *(const f32x4*)(pr + 4)
                           + *(const f32x4*)(pr + 8)  + *(const f32x4*)(pr + 12)
                           + *(const f32x4*)(pr + 16) + *(const f32x4*)(pr + 20);
            const float o = sv[0] + sv[1] + sv[2] + sv[3] + bl;
            if (tid < 16) out[(bb0 + q) * TT + (tau - 1)] = o;
            if (tau < TT) {
                const f32x4 a0 = Aq[0] + Bq[0] + wi0v[0] * o;
                const f32x4 a1 = Aq[1] + Bq[1] + wi0v[1] * o;
                const unsigned h0 = f2h(act1(a0, cc0));
                const unsigned h1 = f2h(act1(a1, cc1));
                s32[(hwp + cb) >> 1] = h0 | (h1 << 16);
            }
        }
        bar_lds();
    }
}

extern "C" void kernel_launch(void* const* d_in, const int* in_sizes, int n_in,
                              void* d_out, int out_size, void* d_ws, size_t ws_size,
                              hipStream_t stream) {
    const float* x    = (const float*)d_in[0];
    const float* Wih0 = (const float*)d_in[1];
    const float* Whh0 = (const float*)d_in[2];
    const float* bih0 = (const float*)d_in[3];
    const float* bhh0 = (const float*)d_in[4];
    const float* Wih1 = (const float*)d_in[5];
    const float* Whh1 = (const float*)d_in[6];
    const float* bih1 = (const float*)d_in[7];
    const float* bhh1 = (const float*)d_in[8];
    const float* Wlin = (const float*)d_in[9];
    const float* blin = (const float*)d_in[10];
    const int*   fut  = (const int*)d_in[11];
    float* out = (float*)d_out;

    const int B    = in_sizes[0] / T_OBS;   // 4096
    const int grid = B / 16;                // 256 blocks -> 1 per CU, 12 waves = 3/SIMD
    lstm2_v10<<<grid, 768, 0, stream>>>(
        x, Wih0, Whh0, bih0, bhh0, Wih1, Whh1, bih1, bhh1, Wlin, blin, fut, out);
}